// Round 12
// baseline (317.639 us; speedup 1.0000x reference)
//
#include <hip/hip_runtime.h>
#include <hip/hip_bf16.h>

#define N_NODES 100000
#define N_EDGES 1600000
#define IN_DIM 256
#define OUT_DIM 128

typedef __attribute__((ext_vector_type(4))) float f32x4;
typedef __attribute__((ext_vector_type(8))) short s16x8;

__device__ inline unsigned short f2bf_us(float f) {
    union { __hip_bfloat16 h; unsigned short u; } v;
    v.h = __float2bfloat16(f);
    return v.u;
}

__device__ inline s16x8 pack8(const float4& a, const float4& b) {
    union { s16x8 v; __hip_bfloat162 h[4]; } u;
    u.h[0] = __float22bfloat162_rn(make_float2(a.x, a.y));
    u.h[1] = __float22bfloat162_rn(make_float2(a.z, a.w));
    u.h[2] = __float22bfloat162_rn(make_float2(b.x, b.y));
    u.h[3] = __float22bfloat162_rn(make_float2(b.z, b.w));
    return u.v;
}

// async global->LDS, 16B per lane; lds dest = wave-uniform base + lane*16
__device__ inline void gload_lds16(const float* g, float* l) {
    __builtin_amdgcn_global_load_lds(
        (const __attribute__((address_space(1))) unsigned*)g,
        (__attribute__((address_space(3))) unsigned*)l, 16, 0, 0);
}

// ------- WTx: wave-order permuted bf16 weights -------------------------------
// WTx[n][kc][kblk][lrow][j] = W[kc*32 + kblk*8 + j][n*16 + lrow]
__global__ __launch_bounds__(256)
void wt_kernel(const float* __restrict__ W, unsigned short* __restrict__ WTx) {
    const int t = blockIdx.x * 256 + threadIdx.x;   // 0..32767, dest-linear
    const int j    = t & 7;
    const int lrow = (t >> 3) & 15;
    const int kblk = (t >> 7) & 3;
    const int kc   = (t >> 9) & 7;
    const int n    = t >> 12;
    const int k    = kc * 32 + kblk * 8 + j;
    const int c    = n * 16 + lrow;
    WTx[t] = f2bf_us(W[(size_t)k * OUT_DIM + c]);
}

// ---------------- GEMM: HWs (bf16, 8 x 16-col slabs) = bf16(H) @ bf16(W) -----
// R10 LDS-staged body (proven ~28us); epilogue now stores SLAB-MAJOR
// (HWs[n][row][16], slab n = cols 16n..16n+15, 3.2 MB each) for the
// XCD-pinned spmm. 2B stores, 16-lane groups write 32B contiguous.
__global__ __launch_bounds__(256, 3)
void gemm_mfma_kernel(const float* __restrict__ H,
                      const unsigned short* __restrict__ WTx,
                      unsigned short* __restrict__ HWs) {
    __shared__ float Hs[2][4096];   // 2 x 16KB = 1024 16B-units per buffer

    const int tid  = threadIdx.x;
    const int wid  = tid >> 6;
    const int lane = tid & 63;
    const int lrow = lane & 15;
    const int kblk = lane >> 4;
    const int brow = blockIdx.x * 128;

    const unsigned short* wbase = WTx + (size_t)(kblk * 16 + lrow) * 8;

    f32x4 acc[2][8] = {};

    auto stage = [&](int b, int kc) {
        #pragma unroll
        for (int i = 0; i < 4; ++i) {
            const int ubase = i * 256 + wid * 64;     // wave-uniform unit base
            const int unit  = ubase + lane;
            const int row   = unit >> 3;
            const int ul    = (unit & 7) ^ (row & 7); // swizzled source unit
            int grow = brow + row; if (grow >= N_NODES) grow = N_NODES - 1;
            const float* gsrc = H + (size_t)grow * IN_DIM + kc * 32 + ul * 4;
            gload_lds16(gsrc, &Hs[b][ubase * 4]);
        }
    };

    stage(0, 0);
    __syncthreads();

    for (int kc = 0; kc < 8; ++kc) {
        const int cur = kc & 1;
        if (kc < 7) stage(cur ^ 1, kc + 1);

        s16x8 fa[2];
        #pragma unroll
        for (int mt = 0; mt < 2; ++mt) {
            const int row = wid * 32 + mt * 16 + lrow;
            const int u0  = (kblk * 2) ^ (row & 7);
            const int u1  = (kblk * 2 + 1) ^ (row & 7);
            const float4 x0 = *(const float4*)&Hs[cur][(row * 8 + u0) * 4];
            const float4 x1 = *(const float4*)&Hs[cur][(row * 8 + u1) * 4];
            fa[mt] = pack8(x0, x1);
        }
        #pragma unroll
        for (int n = 0; n < 8; ++n) {
            const s16x8 fb = *(const s16x8*)(wbase + ((size_t)(n * 8 + kc) << 9));
            acc[0][n] = __builtin_amdgcn_mfma_f32_16x16x32_bf16(fa[0], fb, acc[0][n], 0, 0, 0);
            acc[1][n] = __builtin_amdgcn_mfma_f32_16x16x32_bf16(fa[1], fb, acc[1][n], 0, 0, 0);
        }
        __syncthreads();
    }

    // D layout: col-within-tile = lane&15, row = (lane>>4)*4 + reg.
    // Slab-major store (R5-proven mapping).
    const int c = lane & 15;
    #pragma unroll
    for (int mt = 0; mt < 2; ++mt) {
        #pragma unroll
        for (int r = 0; r < 4; ++r) {
            const int grow = brow + wid * 32 + mt * 16 + (lane >> 4) * 4 + r;
            if (grow < N_NODES) {
                #pragma unroll
                for (int n = 0; n < 8; ++n)
                    HWs[(size_t)n * (N_NODES * 16) + (size_t)grow * 16 + c] =
                        f2bf_us(acc[mt][n][r]);
            }
        }
    }
}

// ---------------- row_ptr from sorted dst ----------------
__global__ __launch_bounds__(256)
void rowptr_kernel(const int* __restrict__ dst, int* __restrict__ row_ptr) {
    const int e = blockIdx.x * blockDim.x + threadIdx.x;
    if (e > N_EDGES) return;
    if (e == N_EDGES) {
        for (int n = dst[N_EDGES - 1] + 1; n <= N_NODES; ++n) row_ptr[n] = N_EDGES;
        return;
    }
    const int d = dst[e];
    const int dprev = (e == 0) ? -1 : dst[e - 1];
    for (int n = dprev + 1; n <= d; ++n) row_ptr[n] = e;
}

// ---------------- SpMM v5: XCD-pinned 16-col slab passes ----------------
// pass = blockIdx.x & 7 -> all blocks of pass p land on XCD p (round-robin
// dispatch; mechanism verified R6: FETCH 274->168 MB). Slab p = 3.2 MB
// < 4 MB per-XCD L2 -> gathers become L2 hits. Wave = 1 node (no degree
// divergence); 8 lanes/edge x 4B = 32B coalesced row; 16 edges/iter.
// Nontemporal meta loads + out stores protect the slab from eviction.
// Disjoint column writes per pass -> atomic-free, deterministic.
__global__ __launch_bounds__(256)
void spmm_v5_kernel(const unsigned int* __restrict__ HWsu,
                    const float* __restrict__ vals,
                    const int* __restrict__ src,
                    const int* __restrict__ row_ptr,
                    const float* __restrict__ bias,
                    float* __restrict__ out) {
    const int p    = blockIdx.x & 7;
    const int node = (blockIdx.x >> 3) * 4 + (threadIdx.x >> 6);
    if (node >= N_NODES) return;
    const int lane  = threadIdx.x & 63;
    const int eslot = lane >> 3;   // 0..7
    const int cg    = lane & 7;    // uint (2 bf16 cols) within 16-col row

    const unsigned int* __restrict__ slab = HWsu + (size_t)p * (N_NODES * 8);

    const int lo = row_ptr[node];
    const int hi = row_ptr[node + 1];

    float ax = 0.f, ay = 0.f;
    for (int base = lo; base < hi; base += 16) {
        const int e0 = base + eslot;
        const int e1 = base + 8 + eslot;
        const bool m0 = e0 < hi, m1 = e1 < hi;
        const int ec0 = m0 ? e0 : lo;
        const int ec1 = m1 ? e1 : lo;
        const int   s0 = __builtin_nontemporal_load(&src[ec0]);
        const int   s1 = __builtin_nontemporal_load(&src[ec1]);
        const float v0 = m0 ? __builtin_nontemporal_load(&vals[ec0]) : 0.f;
        const float v1 = m1 ? __builtin_nontemporal_load(&vals[ec1]) : 0.f;
        const unsigned u0 = slab[(size_t)s0 * 8 + cg];
        const unsigned u1 = slab[(size_t)s1 * 8 + cg];
        ax = fmaf(__uint_as_float(u0 << 16),         v0, ax);
        ay = fmaf(__uint_as_float(u0 & 0xffff0000u), v0, ay);
        ax = fmaf(__uint_as_float(u1 << 16),         v1, ax);
        ay = fmaf(__uint_as_float(u1 & 0xffff0000u), v1, ay);
    }

    // reduce across the 8 eslot groups (lane bits 3,4,5)
    ax += __shfl_xor(ax, 8);  ay += __shfl_xor(ay, 8);
    ax += __shfl_xor(ax, 16); ay += __shfl_xor(ay, 16);
    ax += __shfl_xor(ax, 32); ay += __shfl_xor(ay, 32);

    if (lane < 8) {
        const int c = p * 16 + cg * 2;
        __builtin_nontemporal_store(ax + bias[c],     &out[(size_t)node * OUT_DIM + c]);
        __builtin_nontemporal_store(ay + bias[c + 1], &out[(size_t)node * OUT_DIM + c + 1]);
    }
}

extern "C" void kernel_launch(void* const* d_in, const int* in_sizes, int n_in,
                              void* d_out, int out_size, void* d_ws, size_t ws_size,
                              hipStream_t stream) {
    const float* H    = (const float*)d_in[0];
    const float* W    = (const float*)d_in[1];
    const float* bias = (const float*)d_in[2];
    const float* vals = (const float*)d_in[3];
    const int*   src  = (const int*)d_in[4];
    const int*   dst  = (const int*)d_in[5];
    float* out = (float*)d_out;

    unsigned short* HWs = (unsigned short*)d_ws;   // 25.6 MB bf16, 8 slabs
    const size_t hw_bytes = (size_t)N_NODES * OUT_DIM * sizeof(unsigned short);
    int* row_ptr = (int*)((char*)d_ws + hw_bytes);
    size_t wt_off = hw_bytes + (size_t)(N_NODES + 1) * sizeof(int);
    wt_off = (wt_off + 127) & ~(size_t)127;
    unsigned short* WTx = (unsigned short*)((char*)d_ws + wt_off);

    wt_kernel<<<dim3((IN_DIM * OUT_DIM) / 256), dim3(256), 0, stream>>>(W, WTx);
    rowptr_kernel<<<dim3((N_EDGES + 256) / 256), dim3(256), 0, stream>>>(dst, row_ptr);
    gemm_mfma_kernel<<<dim3((N_NODES + 127) / 128), dim3(256), 0, stream>>>(H, WTx, HWs);

    const int node_blocks = (N_NODES + 3) / 4;     // 25000
    spmm_v5_kernel<<<dim3(node_blocks * 8), dim3(256), 0, stream>>>(
        (const unsigned int*)HWs, vals, src, row_ptr, bias, out);
}

// Round 13
// 237.631 us; speedup vs baseline: 1.3367x; 1.3367x over previous
//
#include <hip/hip_runtime.h>
#include <hip/hip_bf16.h>

#define N_NODES 100000
#define N_EDGES 1600000
#define IN_DIM 256
#define OUT_DIM 128

typedef __attribute__((ext_vector_type(4))) float f32x4;
typedef __attribute__((ext_vector_type(8))) short s16x8;

__device__ inline unsigned short f2bf_us(float f) {
    union { __hip_bfloat16 h; unsigned short u; } v;
    v.h = __float2bfloat16(f);
    return v.u;
}

__device__ inline s16x8 pack8(const float4& a, const float4& b) {
    union { s16x8 v; __hip_bfloat162 h[4]; } u;
    u.h[0] = __float22bfloat162_rn(make_float2(a.x, a.y));
    u.h[1] = __float22bfloat162_rn(make_float2(a.z, a.w));
    u.h[2] = __float22bfloat162_rn(make_float2(b.x, b.y));
    u.h[3] = __float22bfloat162_rn(make_float2(b.z, b.w));
    return u.v;
}

// async global->LDS, 16B per lane; lds dest = wave-uniform base + lane*16
__device__ inline void gload_lds16(const float* g, float* l) {
    __builtin_amdgcn_global_load_lds(
        (const __attribute__((address_space(1))) unsigned*)g,
        (__attribute__((address_space(3))) unsigned*)l, 16, 0, 0);
}

// ------- WTx: wave-order permuted bf16 weights -------------------------------
// WTx[n][kc][kblk][lrow][j] = W[kc*32 + kblk*8 + j][n*16 + lrow]
__global__ __launch_bounds__(256)
void wt_kernel(const float* __restrict__ W, unsigned short* __restrict__ WTx) {
    const int t = blockIdx.x * 256 + threadIdx.x;   // 0..32767, dest-linear
    const int j    = t & 7;
    const int lrow = (t >> 3) & 15;
    const int kblk = (t >> 7) & 3;
    const int kc   = (t >> 9) & 7;
    const int n    = t >> 12;
    const int k    = kc * 32 + kblk * 8 + j;
    const int c    = n * 16 + lrow;
    WTx[t] = f2bf_us(W[(size_t)k * OUT_DIM + c]);
}

// ---------------- GEMM: HWs (bf16, 8 x 16-col slabs) = bf16(H) @ bf16(W) -----
// R10 LDS-staged body (proven ~28us); slab-major epilogue (R12).
__global__ __launch_bounds__(256, 3)
void gemm_mfma_kernel(const float* __restrict__ H,
                      const unsigned short* __restrict__ WTx,
                      unsigned short* __restrict__ HWs) {
    __shared__ float Hs[2][4096];   // 2 x 16KB = 1024 16B-units per buffer

    const int tid  = threadIdx.x;
    const int wid  = tid >> 6;
    const int lane = tid & 63;
    const int lrow = lane & 15;
    const int kblk = lane >> 4;
    const int brow = blockIdx.x * 128;

    const unsigned short* wbase = WTx + (size_t)(kblk * 16 + lrow) * 8;

    f32x4 acc[2][8] = {};

    auto stage = [&](int b, int kc) {
        #pragma unroll
        for (int i = 0; i < 4; ++i) {
            const int ubase = i * 256 + wid * 64;     // wave-uniform unit base
            const int unit  = ubase + lane;
            const int row   = unit >> 3;
            const int ul    = (unit & 7) ^ (row & 7); // swizzled source unit
            int grow = brow + row; if (grow >= N_NODES) grow = N_NODES - 1;
            const float* gsrc = H + (size_t)grow * IN_DIM + kc * 32 + ul * 4;
            gload_lds16(gsrc, &Hs[b][ubase * 4]);
        }
    };

    stage(0, 0);
    __syncthreads();

    for (int kc = 0; kc < 8; ++kc) {
        const int cur = kc & 1;
        if (kc < 7) stage(cur ^ 1, kc + 1);

        s16x8 fa[2];
        #pragma unroll
        for (int mt = 0; mt < 2; ++mt) {
            const int row = wid * 32 + mt * 16 + lrow;
            const int u0  = (kblk * 2) ^ (row & 7);
            const int u1  = (kblk * 2 + 1) ^ (row & 7);
            const float4 x0 = *(const float4*)&Hs[cur][(row * 8 + u0) * 4];
            const float4 x1 = *(const float4*)&Hs[cur][(row * 8 + u1) * 4];
            fa[mt] = pack8(x0, x1);
        }
        #pragma unroll
        for (int n = 0; n < 8; ++n) {
            const s16x8 fb = *(const s16x8*)(wbase + ((size_t)(n * 8 + kc) << 9));
            acc[0][n] = __builtin_amdgcn_mfma_f32_16x16x32_bf16(fa[0], fb, acc[0][n], 0, 0, 0);
            acc[1][n] = __builtin_amdgcn_mfma_f32_16x16x32_bf16(fa[1], fb, acc[1][n], 0, 0, 0);
        }
        __syncthreads();
    }

    const int c = lane & 15;
    #pragma unroll
    for (int mt = 0; mt < 2; ++mt) {
        #pragma unroll
        for (int r = 0; r < 4; ++r) {
            const int grow = brow + wid * 32 + mt * 16 + (lane >> 4) * 4 + r;
            if (grow < N_NODES) {
                #pragma unroll
                for (int n = 0; n < 8; ++n)
                    HWs[(size_t)n * (N_NODES * 16) + (size_t)grow * 16 + c] =
                        f2bf_us(acc[mt][n][r]);
            }
        }
    }
}

// ---------------- row_ptr from sorted dst ----------------
__global__ __launch_bounds__(256)
void rowptr_kernel(const int* __restrict__ dst, int* __restrict__ row_ptr) {
    const int e = blockIdx.x * blockDim.x + threadIdx.x;
    if (e > N_EDGES) return;
    if (e == N_EDGES) {
        for (int n = dst[N_EDGES - 1] + 1; n <= N_NODES; ++n) row_ptr[n] = N_EDGES;
        return;
    }
    const int d = dst[e];
    const int dprev = (e == 0) ? -1 : dst[e - 1];
    for (int n = dprev + 1; n <= d; ++n) row_ptr[n] = e;
}

// ---------------- SpMM v6: XCD-pinned slab passes, latency-repaired ----------
// pass = blockIdx.x & 7 -> XCD p only touches slab p (3.2 MB < 4 MB L2;
// mechanism proven R6/R12: FETCH 185->78 MB). R12 bugs fixed: NO nontemporal
// hints (meta must cache in L3), 32 edges/iter -> 4 slab-gathers in flight.
// Wave = 1 node; 8 lanes/edge x 4B. Disjoint writes, deterministic.
__global__ __launch_bounds__(256)
void spmm_v6_kernel(const unsigned int* __restrict__ HWsu,
                    const float* __restrict__ vals,
                    const int* __restrict__ src,
                    const int* __restrict__ row_ptr,
                    const float* __restrict__ bias,
                    float* __restrict__ out) {
    const int p    = blockIdx.x & 7;
    const int node = (blockIdx.x >> 3) * 4 + (threadIdx.x >> 6);
    if (node >= N_NODES) return;
    const int lane  = threadIdx.x & 63;
    const int eslot = lane >> 3;   // 0..7
    const int cg    = lane & 7;    // uint (2 bf16 cols) within 16-col slab row

    const unsigned int* __restrict__ slab = HWsu + (size_t)p * (N_NODES * 8);

    const int lo = row_ptr[node];
    const int hi = row_ptr[node + 1];

    float ax = 0.f, ay = 0.f;
    for (int base = lo; base < hi; base += 32) {
        int ec[4]; float v[4];
        #pragma unroll
        for (int j = 0; j < 4; ++j) {
            const int e = base + 8 * j + eslot;
            const bool m = e < hi;
            ec[j] = m ? e : lo;
            v[j]  = m ? vals[ec[j]] : 0.f;
        }
        int s[4];
        #pragma unroll
        for (int j = 0; j < 4; ++j) s[j] = src[ec[j]];
        unsigned u[4];
        #pragma unroll
        for (int j = 0; j < 4; ++j) u[j] = slab[(size_t)s[j] * 8 + cg];
        #pragma unroll
        for (int j = 0; j < 4; ++j) {
            ax = fmaf(__uint_as_float(u[j] << 16),         v[j], ax);
            ay = fmaf(__uint_as_float(u[j] & 0xffff0000u), v[j], ay);
        }
    }

    // reduce across the 8 eslot groups (lane bits 3,4,5)
    ax += __shfl_xor(ax, 8);  ay += __shfl_xor(ay, 8);
    ax += __shfl_xor(ax, 16); ay += __shfl_xor(ay, 16);
    ax += __shfl_xor(ax, 32); ay += __shfl_xor(ay, 32);

    if (lane < 8) {
        const int c = p * 16 + cg * 2;
        float2 o;
        o.x = ax + bias[c];
        o.y = ay + bias[c + 1];
        *(float2*)&out[(size_t)node * OUT_DIM + c] = o;
    }
}

extern "C" void kernel_launch(void* const* d_in, const int* in_sizes, int n_in,
                              void* d_out, int out_size, void* d_ws, size_t ws_size,
                              hipStream_t stream) {
    const float* H    = (const float*)d_in[0];
    const float* W    = (const float*)d_in[1];
    const float* bias = (const float*)d_in[2];
    const float* vals = (const float*)d_in[3];
    const int*   src  = (const int*)d_in[4];
    const int*   dst  = (const int*)d_in[5];
    float* out = (float*)d_out;

    unsigned short* HWs = (unsigned short*)d_ws;   // 25.6 MB bf16, 8 slabs
    const size_t hw_bytes = (size_t)N_NODES * OUT_DIM * sizeof(unsigned short);
    int* row_ptr = (int*)((char*)d_ws + hw_bytes);
    size_t wt_off = hw_bytes + (size_t)(N_NODES + 1) * sizeof(int);
    wt_off = (wt_off + 127) & ~(size_t)127;
    unsigned short* WTx = (unsigned short*)((char*)d_ws + wt_off);

    wt_kernel<<<dim3((IN_DIM * OUT_DIM) / 256), dim3(256), 0, stream>>>(W, WTx);
    rowptr_kernel<<<dim3((N_EDGES + 256) / 256), dim3(256), 0, stream>>>(dst, row_ptr);
    gemm_mfma_kernel<<<dim3((N_NODES + 127) / 128), dim3(256), 0, stream>>>(H, WTx, HWs);

    const int node_blocks = (N_NODES + 3) / 4;     // 25000
    spmm_v6_kernel<<<dim3(node_blocks * 8), dim3(256), 0, stream>>>(
        (const unsigned int*)HWs, vals, src, row_ptr, bias, out);
}

// Round 14
// 103.271 us; speedup vs baseline: 3.0758x; 2.3010x over previous
//
#include <hip/hip_runtime.h>
#include <hip/hip_bf16.h>

#define N_NODES 100000
#define N_EDGES 1600000
#define IN_DIM 256
#define OUT_DIM 128

typedef __attribute__((ext_vector_type(4))) float f32x4;
typedef __attribute__((ext_vector_type(8))) short s16x8;

__device__ inline unsigned short f2bf_us(float f) {
    union { __hip_bfloat16 h; unsigned short u; } v;
    v.h = __float2bfloat16(f);
    return v.u;
}

__device__ inline s16x8 pack8(const float4& a, const float4& b) {
    union { s16x8 v; __hip_bfloat162 h[4]; } u;
    u.h[0] = __float22bfloat162_rn(make_float2(a.x, a.y));
    u.h[1] = __float22bfloat162_rn(make_float2(a.z, a.w));
    u.h[2] = __float22bfloat162_rn(make_float2(b.x, b.y));
    u.h[3] = __float22bfloat162_rn(make_float2(b.z, b.w));
    return u.v;
}

// async global->LDS, 16B per lane; lds dest = wave-uniform base + lane*16
__device__ inline void gload_lds16(const float* g, float* l) {
    __builtin_amdgcn_global_load_lds(
        (const __attribute__((address_space(1))) unsigned*)g,
        (__attribute__((address_space(3))) unsigned*)l, 16, 0, 0);
}

// ------- WTx: wave-order permuted bf16 weights -------------------------------
// WTx[n][kc][kblk][lrow][j] = W[kc*32 + kblk*8 + j][n*16 + lrow]
__global__ __launch_bounds__(256)
void wt_kernel(const float* __restrict__ W, unsigned short* __restrict__ WTx) {
    const int t = blockIdx.x * 256 + threadIdx.x;   // 0..32767, dest-linear
    const int j    = t & 7;
    const int lrow = (t >> 3) & 15;
    const int kblk = (t >> 7) & 3;
    const int kc   = (t >> 9) & 7;
    const int n    = t >> 12;
    const int k    = kc * 32 + kblk * 8 + j;
    const int c    = n * 16 + lrow;
    WTx[t] = f2bf_us(W[(size_t)k * OUT_DIM + c]);
}

// ---------------- GEMM: HWp = bf16(H) @ bf16(W), LDS-staged (R10, ~28us) -----
__global__ __launch_bounds__(256, 3)
void gemm_mfma_kernel(const float* __restrict__ H,
                      const unsigned short* __restrict__ WTx,
                      unsigned short* __restrict__ HWp) {
    __shared__ float Hs[2][4096];   // 2 x 16KB = 1024 16B-units per buffer

    const int tid  = threadIdx.x;
    const int wid  = tid >> 6;
    const int lane = tid & 63;
    const int lrow = lane & 15;
    const int kblk = lane >> 4;
    const int brow = blockIdx.x * 128;

    const unsigned short* wbase = WTx + (size_t)(kblk * 16 + lrow) * 8;

    f32x4 acc[2][8] = {};

    auto stage = [&](int b, int kc) {
        #pragma unroll
        for (int i = 0; i < 4; ++i) {
            const int ubase = i * 256 + wid * 64;     // wave-uniform unit base
            const int unit  = ubase + lane;
            const int row   = unit >> 3;
            const int ul    = (unit & 7) ^ (row & 7); // swizzled source unit
            int grow = brow + row; if (grow >= N_NODES) grow = N_NODES - 1;
            const float* gsrc = H + (size_t)grow * IN_DIM + kc * 32 + ul * 4;
            gload_lds16(gsrc, &Hs[b][ubase * 4]);
        }
    };

    stage(0, 0);
    __syncthreads();

    for (int kc = 0; kc < 8; ++kc) {
        const int cur = kc & 1;
        if (kc < 7) stage(cur ^ 1, kc + 1);

        s16x8 fa[2];
        #pragma unroll
        for (int mt = 0; mt < 2; ++mt) {
            const int row = wid * 32 + mt * 16 + lrow;
            const int u0  = (kblk * 2) ^ (row & 7);
            const int u1  = (kblk * 2 + 1) ^ (row & 7);
            const float4 x0 = *(const float4*)&Hs[cur][(row * 8 + u0) * 4];
            const float4 x1 = *(const float4*)&Hs[cur][(row * 8 + u1) * 4];
            fa[mt] = pack8(x0, x1);
        }
        #pragma unroll
        for (int n = 0; n < 8; ++n) {
            const s16x8 fb = *(const s16x8*)(wbase + ((size_t)(n * 8 + kc) << 9));
            acc[0][n] = __builtin_amdgcn_mfma_f32_16x16x32_bf16(fa[0], fb, acc[0][n], 0, 0, 0);
            acc[1][n] = __builtin_amdgcn_mfma_f32_16x16x32_bf16(fa[1], fb, acc[1][n], 0, 0, 0);
        }
        __syncthreads();
    }

    const int c = lane & 15;
    #pragma unroll
    for (int mt = 0; mt < 2; ++mt) {
        #pragma unroll
        for (int r = 0; r < 4; ++r) {
            const int grow = brow + wid * 32 + mt * 16 + (lane >> 4) * 4 + r;
            if (grow < N_NODES) {
                unsigned short tmp[8];
                #pragma unroll
                for (int n = 0; n < 8; ++n) tmp[n] = f2bf_us(acc[mt][n][r]);
                *(s16x8*)(HWp + (size_t)grow * OUT_DIM + c * 8) = *(const s16x8*)tmp;
            }
        }
    }
}

// ---------------- row_ptr from sorted dst ----------------
__global__ __launch_bounds__(256)
void rowptr_kernel(const int* __restrict__ dst, int* __restrict__ row_ptr) {
    const int e = blockIdx.x * blockDim.x + threadIdx.x;
    if (e > N_EDGES) return;
    if (e == N_EDGES) {
        for (int n = dst[N_EDGES - 1] + 1; n <= N_NODES; ++n) row_ptr[n] = N_EDGES;
        return;
    }
    const int d = dst[e];
    const int dprev = (e == 0) ? -1 : dst[e - 1];
    for (int n = dprev + 1; n <= d; ++n) row_ptr[n] = e;
}

// ---------------- SpMM v4: out = A @ HWp + bias ----------------
// Wave = 1 node; eslot = lane>>4 (4 edges/instr), cg = lane&15 (16B of row).
// Unroll x4 -> 16 edges per iteration, 4 uint4 gathers in flight (typical
// node, deg~16, completes in ONE iteration). Deterministic. 67.5us measured;
// FETCH 185 MB = structural minimum for random gather across 8 XCDs.
__global__ __launch_bounds__(256)
void spmm_v4_kernel(const uint4* __restrict__ HWq, const float* __restrict__ vals,
                    const int* __restrict__ src, const int* __restrict__ row_ptr,
                    const float* __restrict__ bias, float* __restrict__ out) {
    const int node = blockIdx.x * 4 + (threadIdx.x >> 6);
    if (node >= N_NODES) return;
    const int lane  = threadIdx.x & 63;
    const int eslot = lane >> 4;   // 0..3
    const int cg    = lane & 15;   // 16B chunk within 256B row

    const int lo = row_ptr[node];
    const int hi = row_ptr[node + 1];

    float acc[8] = {};
    for (int base = lo; base < hi; base += 16) {
        int ec[4]; float v[4];
        #pragma unroll
        for (int j = 0; j < 4; ++j) {
            const int e = base + 4 * j + eslot;
            const bool m = e < hi;
            ec[j] = m ? e : lo;
            v[j]  = m ? vals[ec[j]] : 0.f;
        }
        int s[4];
        #pragma unroll
        for (int j = 0; j < 4; ++j) s[j] = src[ec[j]];
        uint4 g[4];
        #pragma unroll
        for (int j = 0; j < 4; ++j) g[j] = HWq[(size_t)s[j] * 16 + cg];

        #pragma unroll
        for (int j = 0; j < 4; ++j) {
            const unsigned* u = (const unsigned*)&g[j];
            #pragma unroll
            for (int q = 0; q < 4; ++q) {
                acc[2*q]   = fmaf(__uint_as_float(u[q] << 16),         v[j], acc[2*q]);
                acc[2*q+1] = fmaf(__uint_as_float(u[q] & 0xffff0000u), v[j], acc[2*q+1]);
            }
        }
    }

    #pragma unroll
    for (int i = 0; i < 8; ++i) {
        acc[i] += __shfl_xor(acc[i], 16);
        acc[i] += __shfl_xor(acc[i], 32);
    }

    if (lane < 16) {
        #pragma unroll
        for (int j = 0; j < 8; ++j)
            out[(size_t)node * OUT_DIM + j * 16 + cg] = acc[j] + bias[j * 16 + cg];
    }
}

extern "C" void kernel_launch(void* const* d_in, const int* in_sizes, int n_in,
                              void* d_out, int out_size, void* d_ws, size_t ws_size,
                              hipStream_t stream) {
    const float* H    = (const float*)d_in[0];
    const float* W    = (const float*)d_in[1];
    const float* bias = (const float*)d_in[2];
    const float* vals = (const float*)d_in[3];
    const int*   src  = (const int*)d_in[4];
    const int*   dst  = (const int*)d_in[5];
    float* out = (float*)d_out;

    unsigned short* HWp = (unsigned short*)d_ws;   // 25.6 MB bf16, permuted rows
    const size_t hw_bytes = (size_t)N_NODES * OUT_DIM * sizeof(unsigned short);
    int* row_ptr = (int*)((char*)d_ws + hw_bytes);
    size_t wt_off = hw_bytes + (size_t)(N_NODES + 1) * sizeof(int);
    wt_off = (wt_off + 127) & ~(size_t)127;
    unsigned short* WTx = (unsigned short*)((char*)d_ws + wt_off);

    wt_kernel<<<dim3((IN_DIM * OUT_DIM) / 256), dim3(256), 0, stream>>>(W, WTx);
    rowptr_kernel<<<dim3((N_EDGES + 256) / 256), dim3(256), 0, stream>>>(dst, row_ptr);
    gemm_mfma_kernel<<<dim3((N_NODES + 127) / 128), dim3(256), 0, stream>>>(H, WTx, HWp);
    spmm_v4_kernel<<<dim3((N_NODES + 3) / 4), dim3(256), 0, stream>>>(
        (const uint4*)HWp, vals, src, row_ptr, bias, out);
}